// Round 16
// baseline (615.959 us; speedup 1.0000x reference)
//
#include <hip/hip_runtime.h>
#include <hip/hip_bf16.h>

typedef __bf16 bf16;
typedef __attribute__((ext_vector_type(8))) __bf16 bf16x8;
typedef __attribute__((ext_vector_type(2))) __bf16 bf16x2;
typedef __attribute__((ext_vector_type(4))) float f32x4;

#define GLL16(g, l)                                                        \
  __builtin_amdgcn_global_load_lds(                                        \
      (const __attribute__((address_space(1))) unsigned int*)(g),          \
      (__attribute__((address_space(3))) unsigned int*)(l), 16, 0, 0)

// ---------------------------------------------------------------- convert
__global__ void cvt_f32_bf16(const float* __restrict__ in,
                             bf16* __restrict__ out, long n) {
  long i = ((long)blockIdx.x * blockDim.x + threadIdx.x) * 8;
  if (i >= n) return;
  f32x4 a = *reinterpret_cast<const f32x4*>(in + i);
  f32x4 b = *reinterpret_cast<const f32x4*>(in + i + 4);
  bf16x8 o;
  o[0] = (bf16)a[0]; o[1] = (bf16)a[1]; o[2] = (bf16)a[2]; o[3] = (bf16)a[3];
  o[4] = (bf16)b[0]; o[5] = (bf16)b[1]; o[6] = (bf16)b[2]; o[7] = (bf16)b[3];
  *reinterpret_cast<bf16x8*>(out + i) = o;
}

// ---------------------------------------------------------------- GEMM body
// C[M][N] = A[M][K] (bf16, GLL16-staged) * B[N][K]^T (fp32, converted during
// reg-staging). 128x128 tile, 8 waves (2x4 of 64x32), double-buffered.
// LDS layout is [chunk][row] (transposed-chunk map): thread t stages
// (row=t&127, k-chunk=t>>7) so fragment reads (fg*128+row)*16B are 256B
// contiguous per 16-lane group -> 2-way banks (was 8-way with [row][chunk]).
// GLL16 dest stays linear t*16B; only the global SOURCE address changes.
template <typename CT>
__device__ __forceinline__ void gemm_body(const bf16* __restrict__ A,
                                          const float* __restrict__ B,
                                          CT* __restrict__ C,
                                          int bm, int bn, int N, int K) {
  __shared__ __align__(16) bf16 As[2][4096];  // [4 chunk][128 row][8]
  __shared__ __align__(16) bf16 Bs[2][4096];
  const int t = threadIdx.x;        // 0..511
  const int lane = t & 63;
  const int w = t >> 6;             // 0..7
  const int wr = w >> 2, wc = w & 3;
  const int fr = lane & 15, fg = lane >> 4;

  const int sr = t & 127;         // staging row 0..127
  const int sc = (t >> 7) * 8;    // staging k-chunk offset
  const bf16* gA = A + (long)(bm + sr) * K + sc;
  const float* gB = B + (long)(bn + sr) * K + sc;

  f32x4 acc[4][2];
#pragma unroll
  for (int m = 0; m < 4; m++)
#pragma unroll
    for (int n = 0; n < 2; n++) acc[m][n] = (f32x4){0.f, 0.f, 0.f, 0.f};

  auto stageB = [&](int buf, int k0) {
    f32x4 b0 = *reinterpret_cast<const f32x4*>(gB + k0);
    f32x4 b1 = *reinterpret_cast<const f32x4*>(gB + k0 + 4);
    bf16x8 bb;
    bb[0] = (bf16)b0[0]; bb[1] = (bf16)b0[1];
    bb[2] = (bf16)b0[2]; bb[3] = (bf16)b0[3];
    bb[4] = (bf16)b1[0]; bb[5] = (bf16)b1[1];
    bb[6] = (bf16)b1[2]; bb[7] = (bf16)b1[3];
    *reinterpret_cast<bf16x8*>(&Bs[buf][t * 8]) = bb;  // linear write
  };

  {  // prologue: stage k0=0 into buffer 0
    GLL16(gA, &As[0][t * 8]);
    stageB(0, 0);
  }
  int cur = 0;
  for (int k0 = 0; k0 < K; k0 += 32) {
    __syncthreads();  // buf[cur] staged (vmcnt+lgkmcnt drained at barrier)
    if (k0 + 32 < K) {
      GLL16(gA + k0 + 32, &As[cur ^ 1][t * 8]);
      stageB(cur ^ 1, k0 + 32);
    }
    bf16x8 af[4], bfr[2];
#pragma unroll
    for (int m = 0; m < 4; m++)
      af[m] = *reinterpret_cast<const bf16x8*>(
          &As[cur][(fg * 128 + wr * 64 + m * 16 + fr) * 8]);
#pragma unroll
    for (int n = 0; n < 2; n++)
      bfr[n] = *reinterpret_cast<const bf16x8*>(
          &Bs[cur][(fg * 128 + wc * 32 + n * 16 + fr) * 8]);
#pragma unroll
    for (int m = 0; m < 4; m++)
#pragma unroll
      for (int n = 0; n < 2; n++)
        acc[m][n] =
            __builtin_amdgcn_mfma_f32_16x16x32_bf16(af[m], bfr[n], acc[m][n], 0, 0, 0);
    cur ^= 1;
  }
#pragma unroll
  for (int m = 0; m < 4; m++) {
#pragma unroll
    for (int n = 0; n < 2; n++) {
      const int row0 = bm + wr * 64 + m * 16 + fg * 4;
      const int col = bn + wc * 32 + n * 16 + fr;
#pragma unroll
      for (int j = 0; j < 4; j++)
        C[(long)(row0 + j) * N + col] = (CT)acc[m][n][j];
    }
  }
}

template <typename CT>
__global__ __launch_bounds__(512)
void gemm_bt(const bf16* __restrict__ A, const float* __restrict__ B,
             CT* __restrict__ C, int M, int N, int K) {
  gemm_body<CT>(A, B, C, blockIdx.y * 128, blockIdx.x * 128, N, K);
}

// Fused QKV projection: grid (48, 16); per-block uniform operand select.
__global__ __launch_bounds__(512)
void gemm_qkv(const bf16* __restrict__ A, const float* __restrict__ Wq,
              const float* __restrict__ Wk, const float* __restrict__ Wv,
              bf16* __restrict__ qo, bf16* __restrict__ ko,
              bf16* __restrict__ vo) {
  const int nb = blockIdx.x;
  const float* B; bf16* C; int bn, N;
  if (nb < 32)      { B = Wq; C = qo; bn = nb * 128;        N = 4096; }
  else if (nb < 40) { B = Wk; C = ko; bn = (nb - 32) * 128; N = 1024; }
  else              { B = Wv; C = vo; bn = (nb - 40) * 128; N = 1024; }
  gemm_body<bf16>(A, B, C, blockIdx.y * 128, bn, N, 4096);
}

// ---------------------------------------------------------------- RoPE
__global__ void rope_kernel(bf16* __restrict__ q, bf16* __restrict__ k,
                            const int* __restrict__ pos_ids) {
  int idx = blockIdx.x * blockDim.x + threadIdx.x;  // 2048*40*64
  int s = idx / 2560;
  int rem = idx % 2560;
  int hh = rem >> 6;
  int dp = rem & 63;
  float p = (float)pos_ids[s];
  float freq = p * exp2f(-(float)dp * 0.20762050593046025f);
  float cs, sn;
  sincosf(freq, &sn, &cs);
  bf16* base = (hh < 32) ? (q + (long)s * 4096 + hh * 128)
                         : (k + (long)s * 1024 + (hh - 32) * 128);
  float x1 = (float)base[dp], x2 = (float)base[dp + 64];
  base[dp] = (bf16)(x1 * cs - x2 * sn);
  base[dp + 64] = (bf16)(x2 * cs + x1 * sn);
}

// ---------------------------------------------------------------- attention
// q:(2048,4096) k,v:(2048,1024) out:(2048,4096), GQA 4:1, causal.
// KVBLK=64; SINGLE-buffered LDS (40 KB); reg-prefetch overlaps compute.
// LOAD-BALANCE: each block processes the causal-complementary q-tile PAIR
// {bx, 31-bx} -> 33 tiles for EVERY block (round-13: Occupancy 11% was the
// tail of 32-tile blocks running alone; uniform work fixed it, round 14).
// NOTE: no forced min-waves bound — (256,4) twice caused VGPR=64 + scratch
// spill (rounds 8 & 11: WRITE_SIZE 185 MB). (256,2) compiles without spill.
__global__ __launch_bounds__(256, 2)
void attn_fwd(const bf16* __restrict__ qg, const bf16* __restrict__ kg,
              const bf16* __restrict__ vg, bf16* __restrict__ og) {
  const int h = blockIdx.y;
  const int kvh = h >> 2;
  __shared__ __align__(16) bf16 Ks[64 * 128];   // [kv][d], XOR-swizzled
  __shared__ __align__(16) bf16 Vt[128 * 64];   // [d][kv], XOR-swizzled
  __shared__ __align__(16) bf16 Pm[4][16 * 64]; // per-wave P, XOR-swizzled
  const int t = threadIdx.x, lane = t & 63, w = t >> 6;
  const int fr = lane & 15, fg = lane >> 4;
  const float scale = 0.08838834764831845f;

  // staging maps
  const int krow = t >> 2, kcol = (t & 3) * 32;     // K: 1 row, 4x bf16x8
  const int vr = (t & 31) * 2, vd0 = (t >> 5) * 8;  // V: 2 rows, 2 d-halves
  const bf16* gK = kg + kvh * 128;
  const bf16* gV = vg + kvh * 128;

#pragma unroll 1
  for (int half = 0; half < 2; half++) {
    const int qt = half == 0 ? (int)blockIdx.x : 31 - (int)blockIdx.x;
    const int q0 = qt * 64;
    const int wqmax = q0 + w * 16 + 15;
    const int qrow = q0 + w * 16 + fr;
    const int nt = qt + 1;

    bf16x8 aq[4];
#pragma unroll
    for (int c = 0; c < 4; c++)
      aq[c] = *reinterpret_cast<const bf16x8*>(
          &qg[(long)qrow * 4096 + h * 128 + c * 32 + fg * 8]);

    f32x4 oacc[8];
#pragma unroll
    for (int n = 0; n < 8; n++) oacc[n] = (f32x4){0.f, 0.f, 0.f, 0.f};
    float mrow[4], lrow[4];
#pragma unroll
    for (int j = 0; j < 4; j++) { mrow[j] = -INFINITY; lrow[j] = 0.f; }

    bf16x8 kst[4], vst[4];
    {  // prologue loads for tile 0
      const bf16* gk = gK + (long)krow * 1024 + kcol;
#pragma unroll
      for (int i = 0; i < 4; i++)
        kst[i] = *reinterpret_cast<const bf16x8*>(gk + 8 * i);
      const bf16* gv = gV + (long)vr * 1024 + vd0;
      vst[0] = *reinterpret_cast<const bf16x8*>(gv);
      vst[1] = *reinterpret_cast<const bf16x8*>(gv + 64);
      vst[2] = *reinterpret_cast<const bf16x8*>(gv + 1024);
      vst[3] = *reinterpret_cast<const bf16x8*>(gv + 1024 + 64);
    }

    for (int tt = 0; tt < nt; ++tt) {
      const int kv0 = tt * 64;
      // ---- staged regs -> LDS (compiler inserts vmcnt wait on kst/vst)
#pragma unroll
      for (int i = 0; i < 4; i++)
        *reinterpret_cast<bf16x8*>(
            &Ks[krow * 128 + ((kcol + 8 * i) ^ ((krow & 7) << 3))]) = kst[i];
#pragma unroll
      for (int hv = 0; hv < 2; hv++)
#pragma unroll
        for (int j = 0; j < 8; j++) {
          const int d = hv * 64 + vd0 + j;
          bf16x2 pr;
          pr[0] = vst[hv][j];
          pr[1] = vst[2 + hv][j];
          *reinterpret_cast<bf16x2*>(&Vt[d * 64 + (vr ^ ((d & 7) << 3))]) = pr;
        }
      __syncthreads();  // LDS ready for this tile

      // ---- issue next tile's loads into the SAME regs (land during compute)
      if (tt + 1 < nt) {
        const long off = (long)(kv0 + 64) * 1024;
        const bf16* gk = gK + off + (long)krow * 1024 + kcol;
#pragma unroll
        for (int i = 0; i < 4; i++)
          kst[i] = *reinterpret_cast<const bf16x8*>(gk + 8 * i);
        const bf16* gv = gV + off + (long)vr * 1024 + vd0;
        vst[0] = *reinterpret_cast<const bf16x8*>(gv);
        vst[1] = *reinterpret_cast<const bf16x8*>(gv + 64);
        vst[2] = *reinterpret_cast<const bf16x8*>(gv + 1024);
        vst[3] = *reinterpret_cast<const bf16x8*>(gv + 1024 + 64);
      }

      // ---- S = Q K^T  (16 q-rows x 64 kv)
      f32x4 sacc[4];
#pragma unroll
      for (int c = 0; c < 4; c++) sacc[c] = (f32x4){0.f, 0.f, 0.f, 0.f};
#pragma unroll
      for (int c = 0; c < 4; c++) {
        if (kv0 + c * 16 <= wqmax) {  // skip fully-masked chunks (wave-uniform)
#pragma unroll
          for (int kc = 0; kc < 4; kc++) {
            const int row = c * 16 + fr;
            bf16x8 bk = *reinterpret_cast<const bf16x8*>(
                &Ks[row * 128 + ((kc * 32 + fg * 8) ^ ((row & 7) << 3))]);
            sacc[c] =
                __builtin_amdgcn_mfma_f32_16x16x32_bf16(aq[kc], bk, sacc[c], 0, 0, 0);
          }
        }
      }

      // ---- online softmax (rows in 16-lane groups)
#pragma unroll
      for (int j = 0; j < 4; j++) {
        const int qrel = q0 + w * 16 + fg * 4 + j - kv0;
        float s0 = (fr <= qrel) ? sacc[0][j] * scale : -INFINITY;
        float s1 = (16 + fr <= qrel) ? sacc[1][j] * scale : -INFINITY;
        float s2 = (32 + fr <= qrel) ? sacc[2][j] * scale : -INFINITY;
        float s3 = (48 + fr <= qrel) ? sacc[3][j] * scale : -INFINITY;
        float rmax = fmaxf(fmaxf(s0, s1), fmaxf(s2, s3));
#pragma unroll
        for (int off = 1; off < 16; off <<= 1)
          rmax = fmaxf(rmax, __shfl_xor(rmax, off, 64));
        const float mnew = fmaxf(mrow[j], rmax);
        const float alpha = __expf(mrow[j] - mnew);
        mrow[j] = mnew;
        const float p0 = __expf(s0 - mnew);
        const float p1 = __expf(s1 - mnew);
        const float p2 = __expf(s2 - mnew);
        const float p3 = __expf(s3 - mnew);
        float rsum = (p0 + p1) + (p2 + p3);
#pragma unroll
        for (int off = 1; off < 16; off <<= 1) rsum += __shfl_xor(rsum, off, 64);
        lrow[j] = lrow[j] * alpha + rsum;
#pragma unroll
        for (int n = 0; n < 8; n++) oacc[n][j] *= alpha;
        const int prow = fg * 4 + j;
        const int psw = (prow & 7) << 3;
        Pm[w][prow * 64 + (fr ^ psw)] = (bf16)p0;
        Pm[w][prow * 64 + ((16 + fr) ^ psw)] = (bf16)p1;
        Pm[w][prow * 64 + ((32 + fr) ^ psw)] = (bf16)p2;
        Pm[w][prow * 64 + ((48 + fr) ^ psw)] = (bf16)p3;
      }

      // ---- O += P V
      const int asw = (fr & 7) << 3;
      bf16x8 ap0 = *reinterpret_cast<const bf16x8*>(
          &Pm[w][fr * 64 + ((fg * 8) ^ asw)]);
      bf16x8 ap1 = *reinterpret_cast<const bf16x8*>(
          &Pm[w][fr * 64 + ((32 + fg * 8) ^ asw)]);
#pragma unroll
      for (int n = 0; n < 8; n++) {
        const int dr = n * 16 + fr;
        const int dsw = (dr & 7) << 3;
        bf16x8 bv0 = *reinterpret_cast<const bf16x8*>(
            &Vt[dr * 64 + ((fg * 8) ^ dsw)]);
        bf16x8 bv1 = *reinterpret_cast<const bf16x8*>(
            &Vt[dr * 64 + ((32 + fg * 8) ^ dsw)]);
        oacc[n] = __builtin_amdgcn_mfma_f32_16x16x32_bf16(ap0, bv0, oacc[n], 0, 0, 0);
        oacc[n] = __builtin_amdgcn_mfma_f32_16x16x32_bf16(ap1, bv1, oacc[n], 0, 0, 0);
      }
      __syncthreads();  // all reads of Ks/Vt done before next tile's writes
    }

#pragma unroll
    for (int n = 0; n < 8; n++) {
#pragma unroll
      for (int j = 0; j < 4; j++) {
        const int row = q0 + w * 16 + fg * 4 + j;
        const int col = h * 128 + n * 16 + fr;
        og[(long)row * 4096 + col] = (bf16)(oacc[n][j] / lrow[j]);
      }
    }
  }
}

// ---------------------------------------------------------------- launch
extern "C" void kernel_launch(void* const* d_in, const int* in_sizes, int n_in,
                              void* d_out, int out_size, void* d_ws,
                              size_t ws_size, hipStream_t stream) {
  const float* hs = (const float*)d_in[0];
  const int* pos = (const int*)d_in[2];
  const float* Wq = (const float*)d_in[3];
  const float* Wk = (const float*)d_in[4];
  const float* Wv = (const float*)d_in[5];
  const float* Wo = (const float*)d_in[6];

  // ws layout (40 MB, validated):
  //   h_bf [0,16M)  q_bf [16,32M)  k_bf [32,36M)  v_bf [36,40M)
  char* ws = (char*)d_ws;
  bf16* h_bf  = (bf16*)(ws);
  bf16* q_bf  = (bf16*)(ws + 16777216L);
  bf16* k_bf  = (bf16*)(ws + 33554432L);
  bf16* v_bf  = (bf16*)(ws + 37748736L);
  bf16* at_bf = h_bf;  // alias: h_bf dead after QKV projection

  // only hidden needs pre-conversion (A operand, reused by 48 column-tiles)
  cvt_f32_bf16<<<dim3(4096), 256, 0, stream>>>(hs, h_bf, 8388608L);

  gemm_qkv<<<dim3(48, 16), 512, 0, stream>>>(h_bf, Wq, Wk, Wv,
                                             q_bf, k_bf, v_bf);

  rope_kernel<<<dim3(20480), 256, 0, stream>>>(q_bf, k_bf, pos);

  // paired causal tiles: grid.x = 16, each block does q-tiles {bx, 31-bx}
  attn_fwd<<<dim3(16, 32), 256, 0, stream>>>(q_bf, k_bf, v_bf, at_bf);

  // d_out is FLOAT32 — final projection writes fp32 directly.
  gemm_bt<float><<<dim3(32, 16), 512, 0, stream>>>(at_bf, Wo, (float*)d_out,
                                                   2048, 4096, 4096);
}

// Round 17
// 359.511 us; speedup vs baseline: 1.7133x; 1.7133x over previous
//
#include <hip/hip_runtime.h>
#include <hip/hip_bf16.h>

typedef __bf16 bf16;
typedef __attribute__((ext_vector_type(8))) __bf16 bf16x8;
typedef __attribute__((ext_vector_type(2))) __bf16 bf16x2;
typedef __attribute__((ext_vector_type(4))) float f32x4;

// ---------------------------------------------------------------- convert
__global__ void cvt_f32_bf16(const float* __restrict__ in,
                             bf16* __restrict__ out, long n) {
  long i = ((long)blockIdx.x * blockDim.x + threadIdx.x) * 8;
  if (i >= n) return;
  f32x4 a = *reinterpret_cast<const f32x4*>(in + i);
  f32x4 b = *reinterpret_cast<const f32x4*>(in + i + 4);
  bf16x8 o;
  o[0] = (bf16)a[0]; o[1] = (bf16)a[1]; o[2] = (bf16)a[2]; o[3] = (bf16)a[3];
  o[4] = (bf16)b[0]; o[5] = (bf16)b[1]; o[6] = (bf16)b[2]; o[7] = (bf16)b[3];
  *reinterpret_cast<bf16x8*>(out + i) = o;
}

// ---------------------------------------------------------------- GEMM body
// C[M][N] = A[M][K] (bf16) * B[N][K]^T (fp32, converted in staging).
// 128x128 tile, 8 waves (2x4 of 64x32), double-buffered LDS.
// BOTH operands reg-staged (coalesced global loads) and stored in the
// round-16-proven conflict-free layout [chunk][row], with write-XOR:
//   elem (row, k0 + c*8 + e)  ->  LDS[c*1024 + (row ^ (c<<2))*8 + e]
// Reads (16 fr-lanes, fixed chunk fg) and writes are both 2-way (free).
// Pipeline (attn-validated): writes of tile k+1 at iter top (regs loaded a
// full compute-phase earlier), prefetch tile k+2, compute k, one barrier.
template <typename CT>
__device__ __forceinline__ void gemm_body(const bf16* __restrict__ A,
                                          const float* __restrict__ B,
                                          CT* __restrict__ C,
                                          int bm, int bn, int N, int K) {
  __shared__ __align__(16) bf16 As[2][4096];
  __shared__ __align__(16) bf16 Bs[2][4096];
  const int t = threadIdx.x;        // 0..511
  const int lane = t & 63;
  const int w = t >> 6;             // 0..7
  const int wr = w >> 2, wc = w & 3;
  const int fr = lane & 15, fg = lane >> 4;

  const int sr = t >> 2;            // staging row 0..127
  const int sch = t & 3;            // staging k-chunk 0..3
  const int wsl = sch * 1024 + (sr ^ (sch << 2)) * 8;  // LDS write slot
  const bf16* gA = A + (long)(bm + sr) * K + sch * 8;
  const float* gB = B + (long)(bn + sr) * K + sch * 8;

  f32x4 acc[4][2];
#pragma unroll
  for (int m = 0; m < 4; m++)
#pragma unroll
    for (int n = 0; n < 2; n++) acc[m][n] = (f32x4){0.f, 0.f, 0.f, 0.f};

  bf16x8 ra;
  f32x4 rb0, rb1;
  auto loads = [&](int k0) {
    ra = *reinterpret_cast<const bf16x8*>(gA + k0);
    rb0 = *reinterpret_cast<const f32x4*>(gB + k0);
    rb1 = *reinterpret_cast<const f32x4*>(gB + k0 + 4);
  };
  auto writes = [&](int buf) {
    *reinterpret_cast<bf16x8*>(&As[buf][wsl]) = ra;
    bf16x8 bb;
    bb[0] = (bf16)rb0[0]; bb[1] = (bf16)rb0[1];
    bb[2] = (bf16)rb0[2]; bb[3] = (bf16)rb0[3];
    bb[4] = (bf16)rb1[0]; bb[5] = (bf16)rb1[1];
    bb[6] = (bf16)rb1[2]; bb[7] = (bf16)rb1[3];
    *reinterpret_cast<bf16x8*>(&Bs[buf][wsl]) = bb;
  };

  loads(0);
  writes(0);
  loads(32);        // prefetch tile 1 (K >= 64 always here)
  __syncthreads();  // buf0 ready
  int cur = 0;
  for (int k0 = 0; k0 < K; k0 += 32) {
    if (k0 + 32 < K) {
      writes(cur ^ 1);                    // staged regs -> other buffer
      if (k0 + 64 < K) loads(k0 + 64);    // prefetch next (lands during MFMA)
    }
    bf16x8 af[4], bfr[2];
#pragma unroll
    for (int m = 0; m < 4; m++) {
      const int r = wr * 64 + m * 16 + fr;
      af[m] = *reinterpret_cast<const bf16x8*>(
          &As[cur][fg * 1024 + (r ^ (fg << 2)) * 8]);
    }
#pragma unroll
    for (int n = 0; n < 2; n++) {
      const int r = wc * 32 + n * 16 + fr;
      bfr[n] = *reinterpret_cast<const bf16x8*>(
          &Bs[cur][fg * 1024 + (r ^ (fg << 2)) * 8]);
    }
#pragma unroll
    for (int m = 0; m < 4; m++)
#pragma unroll
      for (int n = 0; n < 2; n++)
        acc[m][n] =
            __builtin_amdgcn_mfma_f32_16x16x32_bf16(af[m], bfr[n], acc[m][n], 0, 0, 0);
    __syncthreads();  // reads of buf[cur] done; writes to buf[cur^1] visible
    cur ^= 1;
  }
#pragma unroll
  for (int m = 0; m < 4; m++) {
#pragma unroll
    for (int n = 0; n < 2; n++) {
      const int row0 = bm + wr * 64 + m * 16 + fg * 4;
      const int col = bn + wc * 32 + n * 16 + fr;
#pragma unroll
      for (int j = 0; j < 4; j++)
        C[(long)(row0 + j) * N + col] = (CT)acc[m][n][j];
    }
  }
}

template <typename CT>
__global__ __launch_bounds__(512)
void gemm_bt(const bf16* __restrict__ A, const float* __restrict__ B,
             CT* __restrict__ C, int M, int N, int K) {
  gemm_body<CT>(A, B, C, blockIdx.y * 128, blockIdx.x * 128, N, K);
}

// Fused QKV projection: grid (48, 16); per-block uniform operand select.
__global__ __launch_bounds__(512)
void gemm_qkv(const bf16* __restrict__ A, const float* __restrict__ Wq,
              const float* __restrict__ Wk, const float* __restrict__ Wv,
              bf16* __restrict__ qo, bf16* __restrict__ ko,
              bf16* __restrict__ vo) {
  const int nb = blockIdx.x;
  const float* B; bf16* C; int bn, N;
  if (nb < 32)      { B = Wq; C = qo; bn = nb * 128;        N = 4096; }
  else if (nb < 40) { B = Wk; C = ko; bn = (nb - 32) * 128; N = 1024; }
  else              { B = Wv; C = vo; bn = (nb - 40) * 128; N = 1024; }
  gemm_body<bf16>(A, B, C, blockIdx.y * 128, bn, N, 4096);
}

// ---------------------------------------------------------------- RoPE
__global__ void rope_kernel(bf16* __restrict__ q, bf16* __restrict__ k,
                            const int* __restrict__ pos_ids) {
  int idx = blockIdx.x * blockDim.x + threadIdx.x;  // 2048*40*64
  int s = idx / 2560;
  int rem = idx % 2560;
  int hh = rem >> 6;
  int dp = rem & 63;
  float p = (float)pos_ids[s];
  float freq = p * exp2f(-(float)dp * 0.20762050593046025f);
  float cs, sn;
  sincosf(freq, &sn, &cs);
  bf16* base = (hh < 32) ? (q + (long)s * 4096 + hh * 128)
                         : (k + (long)s * 1024 + (hh - 32) * 128);
  float x1 = (float)base[dp], x2 = (float)base[dp + 64];
  base[dp] = (bf16)(x1 * cs - x2 * sn);
  base[dp + 64] = (bf16)(x2 * cs + x1 * sn);
}

// ---------------------------------------------------------------- attention
// q:(2048,4096) k,v:(2048,1024) out:(2048,4096), GQA 4:1, causal.
// KVBLK=64; SINGLE-buffered LDS (40 KB); reg-prefetch overlaps compute.
// LOAD-BALANCE: each block processes the causal-complementary q-tile PAIR
// {bx, 31-bx} -> 33 tiles for EVERY block (round-13: Occupancy 11% was the
// tail of 32-tile blocks running alone; uniform work fixed it, round 14).
// NOTE: no forced min-waves bound — (256,4) twice caused VGPR=64 + scratch
// spill (rounds 8 & 11: WRITE_SIZE 185 MB). (256,2) compiles without spill.
__global__ __launch_bounds__(256, 2)
void attn_fwd(const bf16* __restrict__ qg, const bf16* __restrict__ kg,
              const bf16* __restrict__ vg, bf16* __restrict__ og) {
  const int h = blockIdx.y;
  const int kvh = h >> 2;
  __shared__ __align__(16) bf16 Ks[64 * 128];   // [kv][d], XOR-swizzled
  __shared__ __align__(16) bf16 Vt[128 * 64];   // [d][kv], XOR-swizzled
  __shared__ __align__(16) bf16 Pm[4][16 * 64]; // per-wave P, XOR-swizzled
  const int t = threadIdx.x, lane = t & 63, w = t >> 6;
  const int fr = lane & 15, fg = lane >> 4;
  const float scale = 0.08838834764831845f;

  // staging maps
  const int krow = t >> 2, kcol = (t & 3) * 32;     // K: 1 row, 4x bf16x8
  const int vr = (t & 31) * 2, vd0 = (t >> 5) * 8;  // V: 2 rows, 2 d-halves
  const bf16* gK = kg + kvh * 128;
  const bf16* gV = vg + kvh * 128;

#pragma unroll 1
  for (int half = 0; half < 2; half++) {
    const int qt = half == 0 ? (int)blockIdx.x : 31 - (int)blockIdx.x;
    const int q0 = qt * 64;
    const int wqmax = q0 + w * 16 + 15;
    const int qrow = q0 + w * 16 + fr;
    const int nt = qt + 1;

    bf16x8 aq[4];
#pragma unroll
    for (int c = 0; c < 4; c++)
      aq[c] = *reinterpret_cast<const bf16x8*>(
          &qg[(long)qrow * 4096 + h * 128 + c * 32 + fg * 8]);

    f32x4 oacc[8];
#pragma unroll
    for (int n = 0; n < 8; n++) oacc[n] = (f32x4){0.f, 0.f, 0.f, 0.f};
    float mrow[4], lrow[4];
#pragma unroll
    for (int j = 0; j < 4; j++) { mrow[j] = -INFINITY; lrow[j] = 0.f; }

    bf16x8 kst[4], vst[4];
    {  // prologue loads for tile 0
      const bf16* gk = gK + (long)krow * 1024 + kcol;
#pragma unroll
      for (int i = 0; i < 4; i++)
        kst[i] = *reinterpret_cast<const bf16x8*>(gk + 8 * i);
      const bf16* gv = gV + (long)vr * 1024 + vd0;
      vst[0] = *reinterpret_cast<const bf16x8*>(gv);
      vst[1] = *reinterpret_cast<const bf16x8*>(gv + 64);
      vst[2] = *reinterpret_cast<const bf16x8*>(gv + 1024);
      vst[3] = *reinterpret_cast<const bf16x8*>(gv + 1024 + 64);
    }

    for (int tt = 0; tt < nt; ++tt) {
      const int kv0 = tt * 64;
      // ---- staged regs -> LDS (compiler inserts vmcnt wait on kst/vst)
#pragma unroll
      for (int i = 0; i < 4; i++)
        *reinterpret_cast<bf16x8*>(
            &Ks[krow * 128 + ((kcol + 8 * i) ^ ((krow & 7) << 3))]) = kst[i];
#pragma unroll
      for (int hv = 0; hv < 2; hv++)
#pragma unroll
        for (int j = 0; j < 8; j++) {
          const int d = hv * 64 + vd0 + j;
          bf16x2 pr;
          pr[0] = vst[hv][j];
          pr[1] = vst[2 + hv][j];
          *reinterpret_cast<bf16x2*>(&Vt[d * 64 + (vr ^ ((d & 7) << 3))]) = pr;
        }
      __syncthreads();  // LDS ready for this tile

      // ---- issue next tile's loads into the SAME regs (land during compute)
      if (tt + 1 < nt) {
        const long off = (long)(kv0 + 64) * 1024;
        const bf16* gk = gK + off + (long)krow * 1024 + kcol;
#pragma unroll
        for (int i = 0; i < 4; i++)
          kst[i] = *reinterpret_cast<const bf16x8*>(gk + 8 * i);
        const bf16* gv = gV + off + (long)vr * 1024 + vd0;
        vst[0] = *reinterpret_cast<const bf16x8*>(gv);
        vst[1] = *reinterpret_cast<const bf16x8*>(gv + 64);
        vst[2] = *reinterpret_cast<const bf16x8*>(gv + 1024);
        vst[3] = *reinterpret_cast<const bf16x8*>(gv + 1024 + 64);
      }

      // ---- S = Q K^T  (16 q-rows x 64 kv)
      f32x4 sacc[4];
#pragma unroll
      for (int c = 0; c < 4; c++) sacc[c] = (f32x4){0.f, 0.f, 0.f, 0.f};
#pragma unroll
      for (int c = 0; c < 4; c++) {
        if (kv0 + c * 16 <= wqmax) {  // skip fully-masked chunks (wave-uniform)
#pragma unroll
          for (int kc = 0; kc < 4; kc++) {
            const int row = c * 16 + fr;
            bf16x8 bk = *reinterpret_cast<const bf16x8*>(
                &Ks[row * 128 + ((kc * 32 + fg * 8) ^ ((row & 7) << 3))]);
            sacc[c] =
                __builtin_amdgcn_mfma_f32_16x16x32_bf16(aq[kc], bk, sacc[c], 0, 0, 0);
          }
        }
      }

      // ---- online softmax (rows in 16-lane groups)
#pragma unroll
      for (int j = 0; j < 4; j++) {
        const int qrel = q0 + w * 16 + fg * 4 + j - kv0;
        float s0 = (fr <= qrel) ? sacc[0][j] * scale : -INFINITY;
        float s1 = (16 + fr <= qrel) ? sacc[1][j] * scale : -INFINITY;
        float s2 = (32 + fr <= qrel) ? sacc[2][j] * scale : -INFINITY;
        float s3 = (48 + fr <= qrel) ? sacc[3][j] * scale : -INFINITY;
        float rmax = fmaxf(fmaxf(s0, s1), fmaxf(s2, s3));
#pragma unroll
        for (int off = 1; off < 16; off <<= 1)
          rmax = fmaxf(rmax, __shfl_xor(rmax, off, 64));
        const float mnew = fmaxf(mrow[j], rmax);
        const float alpha = __expf(mrow[j] - mnew);
        mrow[j] = mnew;
        const float p0 = __expf(s0 - mnew);
        const float p1 = __expf(s1 - mnew);
        const float p2 = __expf(s2 - mnew);
        const float p3 = __expf(s3 - mnew);
        float rsum = (p0 + p1) + (p2 + p3);
#pragma unroll
        for (int off = 1; off < 16; off <<= 1) rsum += __shfl_xor(rsum, off, 64);
        lrow[j] = lrow[j] * alpha + rsum;
#pragma unroll
        for (int n = 0; n < 8; n++) oacc[n][j] *= alpha;
        const int prow = fg * 4 + j;
        const int psw = (prow & 7) << 3;
        Pm[w][prow * 64 + (fr ^ psw)] = (bf16)p0;
        Pm[w][prow * 64 + ((16 + fr) ^ psw)] = (bf16)p1;
        Pm[w][prow * 64 + ((32 + fr) ^ psw)] = (bf16)p2;
        Pm[w][prow * 64 + ((48 + fr) ^ psw)] = (bf16)p3;
      }

      // ---- O += P V
      const int asw = (fr & 7) << 3;
      bf16x8 ap0 = *reinterpret_cast<const bf16x8*>(
          &Pm[w][fr * 64 + ((fg * 8) ^ asw)]);
      bf16x8 ap1 = *reinterpret_cast<const bf16x8*>(
          &Pm[w][fr * 64 + ((32 + fg * 8) ^ asw)]);
#pragma unroll
      for (int n = 0; n < 8; n++) {
        const int dr = n * 16 + fr;
        const int dsw = (dr & 7) << 3;
        bf16x8 bv0 = *reinterpret_cast<const bf16x8*>(
            &Vt[dr * 64 + ((fg * 8) ^ dsw)]);
        bf16x8 bv1 = *reinterpret_cast<const bf16x8*>(
            &Vt[dr * 64 + ((32 + fg * 8) ^ dsw)]);
        oacc[n] = __builtin_amdgcn_mfma_f32_16x16x32_bf16(ap0, bv0, oacc[n], 0, 0, 0);
        oacc[n] = __builtin_amdgcn_mfma_f32_16x16x32_bf16(ap1, bv1, oacc[n], 0, 0, 0);
      }
      __syncthreads();  // all reads of Ks/Vt done before next tile's writes
    }

#pragma unroll
    for (int n = 0; n < 8; n++) {
#pragma unroll
      for (int j = 0; j < 4; j++) {
        const int row = q0 + w * 16 + fg * 4 + j;
        const int col = h * 128 + n * 16 + fr;
        og[(long)row * 4096 + col] = (bf16)(oacc[n][j] / lrow[j]);
      }
    }
  }
}

// ---------------------------------------------------------------- launch
extern "C" void kernel_launch(void* const* d_in, const int* in_sizes, int n_in,
                              void* d_out, int out_size, void* d_ws,
                              size_t ws_size, hipStream_t stream) {
  const float* hs = (const float*)d_in[0];
  const int* pos = (const int*)d_in[2];
  const float* Wq = (const float*)d_in[3];
  const float* Wk = (const float*)d_in[4];
  const float* Wv = (const float*)d_in[5];
  const float* Wo = (const float*)d_in[6];

  // ws layout (40 MB, validated):
  //   h_bf [0,16M)  q_bf [16,32M)  k_bf [32,36M)  v_bf [36,40M)
  char* ws = (char*)d_ws;
  bf16* h_bf  = (bf16*)(ws);
  bf16* q_bf  = (bf16*)(ws + 16777216L);
  bf16* k_bf  = (bf16*)(ws + 33554432L);
  bf16* v_bf  = (bf16*)(ws + 37748736L);
  bf16* at_bf = h_bf;  // alias: h_bf dead after QKV projection

  // only hidden needs pre-conversion (A operand, reused by 48 column-tiles)
  cvt_f32_bf16<<<dim3(4096), 256, 0, stream>>>(hs, h_bf, 8388608L);

  gemm_qkv<<<dim3(48, 16), 512, 0, stream>>>(h_bf, Wq, Wk, Wv,
                                             q_bf, k_bf, v_bf);

  rope_kernel<<<dim3(20480), 256, 0, stream>>>(q_bf, k_bf, pos);

  // paired causal tiles: grid.x = 16, each block does q-tiles {bx, 31-bx}
  attn_fwd<<<dim3(16, 32), 256, 0, stream>>>(q_bf, k_bf, v_bf, at_bf);

  // d_out is FLOAT32 — final projection writes fp32 directly.
  gemm_bt<float><<<dim3(32, 16), 512, 0, stream>>>(at_bf, Wo, (float*)d_out,
                                                   2048, 4096, 4096);
}

// Round 18
// 359.134 us; speedup vs baseline: 1.7151x; 1.0010x over previous
//
#include <hip/hip_runtime.h>
#include <hip/hip_bf16.h>

typedef __bf16 bf16;
typedef __attribute__((ext_vector_type(8))) __bf16 bf16x8;
typedef __attribute__((ext_vector_type(2))) __bf16 bf16x2;
typedef __attribute__((ext_vector_type(4))) float f32x4;

// ---------------------------------------------------------------- convert
__global__ void cvt_f32_bf16(const float* __restrict__ in,
                             bf16* __restrict__ out, long n) {
  long i = ((long)blockIdx.x * blockDim.x + threadIdx.x) * 8;
  if (i >= n) return;
  f32x4 a = *reinterpret_cast<const f32x4*>(in + i);
  f32x4 b = *reinterpret_cast<const f32x4*>(in + i + 4);
  bf16x8 o;
  o[0] = (bf16)a[0]; o[1] = (bf16)a[1]; o[2] = (bf16)a[2]; o[3] = (bf16)a[3];
  o[4] = (bf16)b[0]; o[5] = (bf16)b[1]; o[6] = (bf16)b[2]; o[7] = (bf16)b[3];
  *reinterpret_cast<bf16x8*>(out + i) = o;
}

// ---------------------------------------------------------------- GEMM body
// C[M][N] = A[M][K] (bf16) * B[N][K]^T (fp32, converted in staging).
// 128x128 tile, 8 waves (2x4 of 64x32), double-buffered LDS.
// BOTH operands reg-staged with the COALESCED map (row=t>>2, chunk=t&3:
// 4 lanes cover 64-128B contiguous global) — round-17-validated.
// LDS layout: PADDED [128 row][40 elem] (pad 8 = 16B). Quad index of a 16B
// access at (r*40 + c*8) elems is (5r + c) mod 8; 5 odd -> 16 fr-lanes hit
// all 8 quads twice = 2-way (free). Writes (sr*80+sch*16 B) likewise ~2-way.
// Padding is only possible because staging is register-based (GLL16 cannot
// pad its linear dest — round 16 measured that trade: 0 conflicts but
// uncoalesced sources, +122 us).
template <typename CT>
__device__ __forceinline__ void gemm_body(const bf16* __restrict__ A,
                                          const float* __restrict__ B,
                                          CT* __restrict__ C,
                                          int bm, int bn, int N, int K) {
  __shared__ __align__(16) bf16 As[2][5120];  // [128][40], 10KB each
  __shared__ __align__(16) bf16 Bs[2][5120];
  const int t = threadIdx.x;        // 0..511
  const int lane = t & 63;
  const int w = t >> 6;             // 0..7
  const int wr = w >> 2, wc = w & 3;
  const int fr = lane & 15, fg = lane >> 4;

  const int sr = t >> 2;            // staging row 0..127
  const int sch = t & 3;            // staging k-chunk 0..3
  const int wsl = sr * 40 + sch * 8;  // padded LDS write slot
  const bf16* gA = A + (long)(bm + sr) * K + sch * 8;
  const float* gB = B + (long)(bn + sr) * K + sch * 8;

  f32x4 acc[4][2];
#pragma unroll
  for (int m = 0; m < 4; m++)
#pragma unroll
    for (int n = 0; n < 2; n++) acc[m][n] = (f32x4){0.f, 0.f, 0.f, 0.f};

  bf16x8 ra;
  f32x4 rb0, rb1;
  auto loads = [&](int k0) {
    ra = *reinterpret_cast<const bf16x8*>(gA + k0);
    rb0 = *reinterpret_cast<const f32x4*>(gB + k0);
    rb1 = *reinterpret_cast<const f32x4*>(gB + k0 + 4);
  };
  auto writes = [&](int buf) {
    *reinterpret_cast<bf16x8*>(&As[buf][wsl]) = ra;
    bf16x8 bb;
    bb[0] = (bf16)rb0[0]; bb[1] = (bf16)rb0[1];
    bb[2] = (bf16)rb0[2]; bb[3] = (bf16)rb0[3];
    bb[4] = (bf16)rb1[0]; bb[5] = (bf16)rb1[1];
    bb[6] = (bf16)rb1[2]; bb[7] = (bf16)rb1[3];
    *reinterpret_cast<bf16x8*>(&Bs[buf][wsl]) = bb;
  };

  loads(0);
  writes(0);
  loads(32);        // prefetch tile 1 (K >= 64 always here)
  __syncthreads();  // buf0 ready
  int cur = 0;
  for (int k0 = 0; k0 < K; k0 += 32) {
    if (k0 + 32 < K) {
      writes(cur ^ 1);                    // staged regs -> other buffer
      if (k0 + 64 < K) loads(k0 + 64);    // prefetch next (lands during MFMA)
    }
    bf16x8 af[4], bfr[2];
#pragma unroll
    for (int m = 0; m < 4; m++) {
      const int r = wr * 64 + m * 16 + fr;
      af[m] = *reinterpret_cast<const bf16x8*>(&As[cur][r * 40 + fg * 8]);
    }
#pragma unroll
    for (int n = 0; n < 2; n++) {
      const int r = wc * 32 + n * 16 + fr;
      bfr[n] = *reinterpret_cast<const bf16x8*>(&Bs[cur][r * 40 + fg * 8]);
    }
#pragma unroll
    for (int m = 0; m < 4; m++)
#pragma unroll
      for (int n = 0; n < 2; n++)
        acc[m][n] =
            __builtin_amdgcn_mfma_f32_16x16x32_bf16(af[m], bfr[n], acc[m][n], 0, 0, 0);
    __syncthreads();  // reads of buf[cur] done; writes to buf[cur^1] visible
    cur ^= 1;
  }
#pragma unroll
  for (int m = 0; m < 4; m++) {
#pragma unroll
    for (int n = 0; n < 2; n++) {
      const int row0 = bm + wr * 64 + m * 16 + fg * 4;
      const int col = bn + wc * 32 + n * 16 + fr;
#pragma unroll
      for (int j = 0; j < 4; j++)
        C[(long)(row0 + j) * N + col] = (CT)acc[m][n][j];
    }
  }
}

template <typename CT>
__global__ __launch_bounds__(512)
void gemm_bt(const bf16* __restrict__ A, const float* __restrict__ B,
             CT* __restrict__ C, int M, int N, int K) {
  gemm_body<CT>(A, B, C, blockIdx.y * 128, blockIdx.x * 128, N, K);
}

// Fused QKV projection: grid (48, 16); per-block uniform operand select.
__global__ __launch_bounds__(512)
void gemm_qkv(const bf16* __restrict__ A, const float* __restrict__ Wq,
              const float* __restrict__ Wk, const float* __restrict__ Wv,
              bf16* __restrict__ qo, bf16* __restrict__ ko,
              bf16* __restrict__ vo) {
  const int nb = blockIdx.x;
  const float* B; bf16* C; int bn, N;
  if (nb < 32)      { B = Wq; C = qo; bn = nb * 128;        N = 4096; }
  else if (nb < 40) { B = Wk; C = ko; bn = (nb - 32) * 128; N = 1024; }
  else              { B = Wv; C = vo; bn = (nb - 40) * 128; N = 1024; }
  gemm_body<bf16>(A, B, C, blockIdx.y * 128, bn, N, 4096);
}

// ---------------------------------------------------------------- RoPE
__global__ void rope_kernel(bf16* __restrict__ q, bf16* __restrict__ k,
                            const int* __restrict__ pos_ids) {
  int idx = blockIdx.x * blockDim.x + threadIdx.x;  // 2048*40*64
  int s = idx / 2560;
  int rem = idx % 2560;
  int hh = rem >> 6;
  int dp = rem & 63;
  float p = (float)pos_ids[s];
  float freq = p * exp2f(-(float)dp * 0.20762050593046025f);
  float cs, sn;
  sincosf(freq, &sn, &cs);
  bf16* base = (hh < 32) ? (q + (long)s * 4096 + hh * 128)
                         : (k + (long)s * 1024 + (hh - 32) * 128);
  float x1 = (float)base[dp], x2 = (float)base[dp + 64];
  base[dp] = (bf16)(x1 * cs - x2 * sn);
  base[dp + 64] = (bf16)(x2 * cs + x1 * sn);
}

// ---------------------------------------------------------------- attention
// q:(2048,4096) k,v:(2048,1024) out:(2048,4096), GQA 4:1, causal.
// KVBLK=64; SINGLE-buffered LDS (40 KB); reg-prefetch overlaps compute.
// LOAD-BALANCE: each block processes the causal-complementary q-tile PAIR
// {bx, 31-bx} -> 33 tiles for EVERY block (round-13: Occupancy 11% was the
// tail of 32-tile blocks running alone; uniform work fixed it, round 14).
// NOTE: no forced min-waves bound — (256,4) twice caused VGPR=64 + scratch
// spill (rounds 8 & 11: WRITE_SIZE 185 MB). (256,2) compiles without spill.
__global__ __launch_bounds__(256, 2)
void attn_fwd(const bf16* __restrict__ qg, const bf16* __restrict__ kg,
              const bf16* __restrict__ vg, bf16* __restrict__ og) {
  const int h = blockIdx.y;
  const int kvh = h >> 2;
  __shared__ __align__(16) bf16 Ks[64 * 128];   // [kv][d], XOR-swizzled
  __shared__ __align__(16) bf16 Vt[128 * 64];   // [d][kv], XOR-swizzled
  __shared__ __align__(16) bf16 Pm[4][16 * 64]; // per-wave P, XOR-swizzled
  const int t = threadIdx.x, lane = t & 63, w = t >> 6;
  const int fr = lane & 15, fg = lane >> 4;
  const float scale = 0.08838834764831845f;

  // staging maps
  const int krow = t >> 2, kcol = (t & 3) * 32;     // K: 1 row, 4x bf16x8
  const int vr = (t & 31) * 2, vd0 = (t >> 5) * 8;  // V: 2 rows, 2 d-halves
  const bf16* gK = kg + kvh * 128;
  const bf16* gV = vg + kvh * 128;

#pragma unroll 1
  for (int half = 0; half < 2; half++) {
    const int qt = half == 0 ? (int)blockIdx.x : 31 - (int)blockIdx.x;
    const int q0 = qt * 64;
    const int wqmax = q0 + w * 16 + 15;
    const int qrow = q0 + w * 16 + fr;
    const int nt = qt + 1;

    bf16x8 aq[4];
#pragma unroll
    for (int c = 0; c < 4; c++)
      aq[c] = *reinterpret_cast<const bf16x8*>(
          &qg[(long)qrow * 4096 + h * 128 + c * 32 + fg * 8]);

    f32x4 oacc[8];
#pragma unroll
    for (int n = 0; n < 8; n++) oacc[n] = (f32x4){0.f, 0.f, 0.f, 0.f};
    float mrow[4], lrow[4];
#pragma unroll
    for (int j = 0; j < 4; j++) { mrow[j] = -INFINITY; lrow[j] = 0.f; }

    bf16x8 kst[4], vst[4];
    {  // prologue loads for tile 0
      const bf16* gk = gK + (long)krow * 1024 + kcol;
#pragma unroll
      for (int i = 0; i < 4; i++)
        kst[i] = *reinterpret_cast<const bf16x8*>(gk + 8 * i);
      const bf16* gv = gV + (long)vr * 1024 + vd0;
      vst[0] = *reinterpret_cast<const bf16x8*>(gv);
      vst[1] = *reinterpret_cast<const bf16x8*>(gv + 64);
      vst[2] = *reinterpret_cast<const bf16x8*>(gv + 1024);
      vst[3] = *reinterpret_cast<const bf16x8*>(gv + 1024 + 64);
    }

    for (int tt = 0; tt < nt; ++tt) {
      const int kv0 = tt * 64;
      // ---- staged regs -> LDS (compiler inserts vmcnt wait on kst/vst)
#pragma unroll
      for (int i = 0; i < 4; i++)
        *reinterpret_cast<bf16x8*>(
            &Ks[krow * 128 + ((kcol + 8 * i) ^ ((krow & 7) << 3))]) = kst[i];
#pragma unroll
      for (int hv = 0; hv < 2; hv++)
#pragma unroll
        for (int j = 0; j < 8; j++) {
          const int d = hv * 64 + vd0 + j;
          bf16x2 pr;
          pr[0] = vst[hv][j];
          pr[1] = vst[2 + hv][j];
          *reinterpret_cast<bf16x2*>(&Vt[d * 64 + (vr ^ ((d & 7) << 3))]) = pr;
        }
      __syncthreads();  // LDS ready for this tile

      // ---- issue next tile's loads into the SAME regs (land during compute)
      if (tt + 1 < nt) {
        const long off = (long)(kv0 + 64) * 1024;
        const bf16* gk = gK + off + (long)krow * 1024 + kcol;
#pragma unroll
        for (int i = 0; i < 4; i++)
          kst[i] = *reinterpret_cast<const bf16x8*>(gk + 8 * i);
        const bf16* gv = gV + off + (long)vr * 1024 + vd0;
        vst[0] = *reinterpret_cast<const bf16x8*>(gv);
        vst[1] = *reinterpret_cast<const bf16x8*>(gv + 64);
        vst[2] = *reinterpret_cast<const bf16x8*>(gv + 1024);
        vst[3] = *reinterpret_cast<const bf16x8*>(gv + 1024 + 64);
      }

      // ---- S = Q K^T  (16 q-rows x 64 kv)
      f32x4 sacc[4];
#pragma unroll
      for (int c = 0; c < 4; c++) sacc[c] = (f32x4){0.f, 0.f, 0.f, 0.f};
#pragma unroll
      for (int c = 0; c < 4; c++) {
        if (kv0 + c * 16 <= wqmax) {  // skip fully-masked chunks (wave-uniform)
#pragma unroll
          for (int kc = 0; kc < 4; kc++) {
            const int row = c * 16 + fr;
            bf16x8 bk = *reinterpret_cast<const bf16x8*>(
                &Ks[row * 128 + ((kc * 32 + fg * 8) ^ ((row & 7) << 3))]);
            sacc[c] =
                __builtin_amdgcn_mfma_f32_16x16x32_bf16(aq[kc], bk, sacc[c], 0, 0, 0);
          }
        }
      }

      // ---- online softmax (rows in 16-lane groups)
#pragma unroll
      for (int j = 0; j < 4; j++) {
        const int qrel = q0 + w * 16 + fg * 4 + j - kv0;
        float s0 = (fr <= qrel) ? sacc[0][j] * scale : -INFINITY;
        float s1 = (16 + fr <= qrel) ? sacc[1][j] * scale : -INFINITY;
        float s2 = (32 + fr <= qrel) ? sacc[2][j] * scale : -INFINITY;
        float s3 = (48 + fr <= qrel) ? sacc[3][j] * scale : -INFINITY;
        float rmax = fmaxf(fmaxf(s0, s1), fmaxf(s2, s3));
#pragma unroll
        for (int off = 1; off < 16; off <<= 1)
          rmax = fmaxf(rmax, __shfl_xor(rmax, off, 64));
        const float mnew = fmaxf(mrow[j], rmax);
        const float alpha = __expf(mrow[j] - mnew);
        mrow[j] = mnew;
        const float p0 = __expf(s0 - mnew);
        const float p1 = __expf(s1 - mnew);
        const float p2 = __expf(s2 - mnew);
        const float p3 = __expf(s3 - mnew);
        float rsum = (p0 + p1) + (p2 + p3);
#pragma unroll
        for (int off = 1; off < 16; off <<= 1) rsum += __shfl_xor(rsum, off, 64);
        lrow[j] = lrow[j] * alpha + rsum;
#pragma unroll
        for (int n = 0; n < 8; n++) oacc[n][j] *= alpha;
        const int prow = fg * 4 + j;
        const int psw = (prow & 7) << 3;
        Pm[w][prow * 64 + (fr ^ psw)] = (bf16)p0;
        Pm[w][prow * 64 + ((16 + fr) ^ psw)] = (bf16)p1;
        Pm[w][prow * 64 + ((32 + fr) ^ psw)] = (bf16)p2;
        Pm[w][prow * 64 + ((48 + fr) ^ psw)] = (bf16)p3;
      }

      // ---- O += P V
      const int asw = (fr & 7) << 3;
      bf16x8 ap0 = *reinterpret_cast<const bf16x8*>(
          &Pm[w][fr * 64 + ((fg * 8) ^ asw)]);
      bf16x8 ap1 = *reinterpret_cast<const bf16x8*>(
          &Pm[w][fr * 64 + ((32 + fg * 8) ^ asw)]);
#pragma unroll
      for (int n = 0; n < 8; n++) {
        const int dr = n * 16 + fr;
        const int dsw = (dr & 7) << 3;
        bf16x8 bv0 = *reinterpret_cast<const bf16x8*>(
            &Vt[dr * 64 + ((fg * 8) ^ dsw)]);
        bf16x8 bv1 = *reinterpret_cast<const bf16x8*>(
            &Vt[dr * 64 + ((32 + fg * 8) ^ dsw)]);
        oacc[n] = __builtin_amdgcn_mfma_f32_16x16x32_bf16(ap0, bv0, oacc[n], 0, 0, 0);
        oacc[n] = __builtin_amdgcn_mfma_f32_16x16x32_bf16(ap1, bv1, oacc[n], 0, 0, 0);
      }
      __syncthreads();  // all reads of Ks/Vt done before next tile's writes
    }

#pragma unroll
    for (int n = 0; n < 8; n++) {
#pragma unroll
      for (int j = 0; j < 4; j++) {
        const int row = q0 + w * 16 + fg * 4 + j;
        const int col = h * 128 + n * 16 + fr;
        og[(long)row * 4096 + col] = (bf16)(oacc[n][j] / lrow[j]);
      }
    }
  }
}

// ---------------------------------------------------------------- launch
extern "C" void kernel_launch(void* const* d_in, const int* in_sizes, int n_in,
                              void* d_out, int out_size, void* d_ws,
                              size_t ws_size, hipStream_t stream) {
  const float* hs = (const float*)d_in[0];
  const int* pos = (const int*)d_in[2];
  const float* Wq = (const float*)d_in[3];
  const float* Wk = (const float*)d_in[4];
  const float* Wv = (const float*)d_in[5];
  const float* Wo = (const float*)d_in[6];

  // ws layout (40 MB, validated):
  //   h_bf [0,16M)  q_bf [16,32M)  k_bf [32,36M)  v_bf [36,40M)
  char* ws = (char*)d_ws;
  bf16* h_bf  = (bf16*)(ws);
  bf16* q_bf  = (bf16*)(ws + 16777216L);
  bf16* k_bf  = (bf16*)(ws + 33554432L);
  bf16* v_bf  = (bf16*)(ws + 37748736L);
  bf16* at_bf = h_bf;  // alias: h_bf dead after QKV projection

  // only hidden needs pre-conversion (A operand, reused by 48 column-tiles)
  cvt_f32_bf16<<<dim3(4096), 256, 0, stream>>>(hs, h_bf, 8388608L);

  gemm_qkv<<<dim3(48, 16), 512, 0, stream>>>(h_bf, Wq, Wk, Wv,
                                             q_bf, k_bf, v_bf);

  rope_kernel<<<dim3(20480), 256, 0, stream>>>(q_bf, k_bf, pos);

  // paired causal tiles: grid.x = 16, each block does q-tiles {bx, 31-bx}
  attn_fwd<<<dim3(16, 32), 256, 0, stream>>>(q_bf, k_bf, v_bf, at_bf);

  // d_out is FLOAT32 — final projection writes fp32 directly.
  gemm_bt<float><<<dim3(32, 16), 512, 0, stream>>>(at_bf, Wo, (float*)d_out,
                                                   2048, 4096, 4096);
}